// Round 19
// baseline (318.281 us; speedup 1.0000x reference)
//
#include <hip/hip_runtime.h>
#include <hip/hip_bf16.h>

// SO2Linear, round 19: r16 with __launch_bounds__(512,3).
//   Counter analysis r15 vs r16: kernel naturally needs ~72 VGPRs.
//   (512,4) -> compiler caps 64, spills 104MB (WRITE 368MB), 2 blocks, 313us.
//   (512,2) -> 72 regs, no spill, but 1 block resident, 336us.
//   (512,3) targets the untested point: ~72-84 regs (no spill) AND 2 blocks
//   resident (LDS-capped at 2; 72 regs admits 7 waves/SIMD >= 4 needed).
// Everything else byte-identical to r16/r18 (best: 292.5us wall).

#define EPB 16
#define BRICK_USHORTS 294912
#define WS_NEED (589824 + 16)

typedef __attribute__((ext_vector_type(8))) short short8v;
typedef __attribute__((ext_vector_type(4))) float float4v;
typedef unsigned short ushort;

__device__ __forceinline__ float bf2f(__hip_bfloat16 v) { return __bfloat162float(v); }
__device__ __forceinline__ ushort f2bb(float v) {
    __hip_bfloat16 h = __float2bfloat16(v);
    return *reinterpret_cast<ushort*>(&h);
}
__device__ __forceinline__ float bb2f(ushort u) {
    __hip_bfloat16 h = *reinterpret_cast<__hip_bfloat16*>(&u);
    return __bfloat162float(h);
}

// ---- wave-parallel trio classification ----
// 0 = mask (boolean), 1 = W0 (0.05-scale), 2 = D0 (unit-scale)
__device__ int classify_wave(const void* p, int lane)
{
    const unsigned char* b = (const unsigned char*)p;
    bool ok01 = true;
    #pragma unroll
    for (int j = 0; j < 4; ++j) if (b[lane * 4 + j] > 1) ok01 = false;
    if (__all(ok01)) return 0;
    const unsigned* w = (const unsigned*)p;
    const unsigned v = w[lane];
    const unsigned lo = v & 0xFFFFu, hi = v >> 16;
    const bool f32b  = (v == 0u || v == 0x3F800000u);
    const bool bf16b = (lo == 0u || lo == 0x3F80u) && (hi == 0u || hi == 0x3F80u);
    const bool f16b  = (lo == 0u || lo == 0x3C00u) && (hi == 0u || hi == 0x3C00u);
    if (__all(f32b) | __all(bf16b) | __all(f16b)) return 0;
    const float* f = (const float*)p;
    float mx = 0.f;
    #pragma unroll
    for (int j = 0; j < 4; ++j) mx = fmaxf(mx, fabsf(f[lane * 4 + j]));
    #pragma unroll
    for (int d = 1; d < 64; d <<= 1) mx = fmaxf(mx, __shfl_xor(mx, d));
    return (mx < 0.35f) ? 1 : 2;
}

__device__ int detect_stride_wave(const unsigned char* mb, int lane)
{
    unsigned orr[8] = {0,0,0,0,0,0,0,0};
    unsigned maxb = 0, minnz = 255;
    #pragma unroll
    for (int j = 0; j < 16; ++j) {
        unsigned v = mb[lane * 16 + j];
        orr[j & 7] |= v;
        if (v) { maxb = max(maxb, v); minnz = min(minnz, v); }
    }
    #pragma unroll
    for (int d = 1; d < 64; d <<= 1) {
        #pragma unroll
        for (int r = 0; r < 8; ++r) orr[r] |= (unsigned)__shfl_xor((int)orr[r], d);
        maxb  = max(maxb, (unsigned)__shfl_xor((int)maxb, d));
        minnz = min(minnz, (unsigned)__shfl_xor((int)minnz, d));
    }
    const unsigned oddnz = orr[1] | orr[3] | orr[5] | orr[7];
    const bool intbool = (maxb <= 1u) || (maxb == 255u && minnz == 255u);
    if (intbool) {
        if (oddnz)                  return 1;
        else if (orr[2] | orr[6])   return 2;
        else if (orr[4])            return 4;
        else                        return 8;
    } else {
        if (orr[0])                 return 2;
        else if (orr[1])            return 2;
        else if (orr[2])            return 4;
        else                        return 8;
    }
}

// ---------------- prep: pack Bhat bricks + write routing header ----------------
__global__ void so2_prep(const void* t0, const void* t1, const void* t2,
                         const float* __restrict__ W1,
                         const float* __restrict__ W2,
                         const float* __restrict__ W3,
                         ushort* __restrict__ Bb)
{
    const int lane = threadIdx.x;            // blockDim = 64, one wave
    const int c0 = classify_wave(t0, lane);
    const int c1 = classify_wave(t1, lane);
    const int c2 = classify_wave(t2, lane);
    const void* sel[3];
    int im, id;
    if (c0 != c1 && c0 != c2 && c1 != c2) {
        sel[c0] = t0; sel[c1] = t1; sel[c2] = t2;
        im = (c0 == 0) ? 0 : (c1 == 0) ? 1 : 2;
        id = (c0 == 2) ? 0 : (c1 == 2) ? 1 : 2;
    } else {
        sel[2] = t0; sel[0] = t1; sel[1] = t2;   // dict-order fallback
        im = 1; id = 0;
    }
    const float* sW0 = (const float*)sel[1];
    if (blockIdx.x == 0) {
        const int stride = detect_stride_wave((const unsigned char*)sel[0], lane);
        if (lane == 0) {
            int* hdr = (int*)(Bb + BRICK_USHORTS);
            hdr[0] = im; hdr[1] = id; hdr[2] = stride;
        }
    }

    const int brick = blockIdx.x;            // 576 bricks
    int m, r, KT;
    if (brick < 128)      { m = 0; r = brick;       KT = 8;  }
    else if (brick < 416) { m = 1; r = brick - 128; KT = 12; }
    else if (brick < 544) { m = 2; r = brick - 416; KT = 8;  }
    else                  { m = 3; r = brick - 544; KT = 4;  }
    const int nt = r / KT, kt = r - nt * KT;
    const float* Wm = (m == 0) ? sW0 : (m == 1) ? W1 : (m == 2) ? W2 : W3;
    const int c = (m == 0) ? 256 : (m == 1) ? 192 : (m == 2) ? 128 : 64;

    const int col = nt * 16 + (lane & 15);
    const int kb  = kt * 32 + (lane >> 4) * 8;
    ushort* dst = Bb + ((size_t)brick << 9) + lane * 8;
    #pragma unroll
    for (int i = 0; i < 8; ++i) {
        const int k = kb + i;
        float v;
        if (m == 0) v = Wm[(size_t)col * 256 + k];
        else if (col < c) v = (k < c) ? Wm[(size_t)col * c + k]
                                      : Wm[(size_t)(c + col) * c + (k - c)];
        else {
            const int o = col - c;
            v = (k < c) ? -Wm[(size_t)(c + o) * c + k]
                        :  Wm[(size_t)o * c + (k - c)];
        }
        dst[i] = f2bb(v);
    }
}

// ---------------- phase-B unit (compile-time M/KT, chunk-4 brick prefetch) -----
template<int M>
__device__ __forceinline__ void run_unit(
    const ushort (*A_lds)[1024], ushort (*Y_lds)[1024],
    const ushort* __restrict__ Bb,
    const float* __restrict__ weightp, const float* __restrict__ b0,
    const float* me_sh, int e0, int nt, int lane)
{
    constexpr int KT   = (M == 0) ? 8 : (M == 1) ? 12 : (M == 2) ? 8 : 4;
    constexpr int segk = (M == 0) ? 0 : (M == 1) ? 256 : (M == 2) ? 640 : 896;
    constexpr int c    = (M == 0) ? 256 : (M == 1) ? 192 : (M == 2) ? 128 : 64;
    constexpr int wsl  = (M == 0) ? 0 : (M == 1) ? 256 : (M == 2) ? 448 : 576;
    constexpr int bb   = (M == 0) ? 0 : (M == 1) ? 128 : (M == 2) ? 416 : 544;

    const int row16 = lane & 15;
    const int kg    = lane >> 4;
    const int sw    = (row16 & 7) << 3;

    const ushort* bp = Bb + (((size_t)(bb + nt * KT)) << 9) + lane * 8;
    const int k0 = segk + kg * 8;
    float4v acc = {0.f, 0.f, 0.f, 0.f};

    #pragma unroll
    for (int kc = 0; kc < KT; kc += 4) {     // chunked prefetch: 16 VGPRs peak
        short8v bv[4];
        #pragma unroll
        for (int q = 0; q < 4; ++q)
            bv[q] = *(const short8v*)(bp + (size_t)(kc + q) * 512);
        #pragma unroll
        for (int q = 0; q < 4; ++q) {
            short8v av = *(const short8v*)&A_lds[row16][(k0 + (kc + q) * 32) ^ sw];
            acc = __builtin_amdgcn_mfma_f32_16x16x32_bf16(av, bv[q], acc, 0, 0, 0);
        }
    }

    const int j  = nt * 16 + row16;
    const int wo = (j < c) ? j : j - c;
    int tgt;
    if (M == 0) { const int l = j >> 6, ch = j & 63; tgt = 64*l*l + l + ch*(2*l+1); }
    else {
        const int p = j >> 1, s = j & 1;
        const int l = M + (p >> 6), ch = p & 63;
        tgt = 64*l*l + l + ch*(2*l+1) + (s ? M : -M);
    }
    const float bias = (M == 0) ? b0[j] : 0.f;
    #pragma unroll
    for (int r = 0; r < 4; ++r) {
        const int e = kg * 4 + r;
        const float v = (acc[r] + bias)
                      * weightp[(size_t)(e0 + e) * 640 + wsl + wo]
                      * me_sh[e];
        Y_lds[e][tgt] = f2bb(v);
    }
}

// ---------------- main MFMA kernel ----------------
__launch_bounds__(512, 3)
__global__ void so2_mfma(const float* __restrict__ x,
                         const void* __restrict__ t0,
                         const void* __restrict__ t1,
                         const void* __restrict__ t2,
                         const float* __restrict__ D1p,
                         const float* __restrict__ D2p,
                         const float* __restrict__ D3p,
                         const float* __restrict__ weightp,
                         const float* __restrict__ b0,
                         const ushort* __restrict__ Bb,
                         float* __restrict__ out)
{
    __shared__ ushort A_lds[EPB][1024];      // 32 KB
    __shared__ ushort Y_lds[EPB][1024];      // 32 KB
    __shared__ float Dsh[EPB][84];
    __shared__ float me_sh[EPB];
    __shared__ int   mm_sh;
    __shared__ const void*  sel_mask;
    __shared__ const float* sel_D0;

    const int tid  = threadIdx.x;
    const int e0   = blockIdx.x * EPB;
    const int w    = tid >> 6;               // wave 0..7
    const int lane = tid & 63;

    if (tid == 0) {
        const int* hdr = (const int*)(Bb + BRICK_USHORTS);
        const void* tarr[3] = {t0, t1, t2};
        sel_mask = tarr[hdr[0]];
        sel_D0   = (const float*)tarr[hdr[1]];
        mm_sh    = hdr[2];
    }
    __syncthreads();

    const float* D0p   = sel_D0;
    const void*  maskp = sel_mask;

    for (int idx = tid; idx < EPB * 84; idx += 512) {
        int le = idx / 84, d = idx - le * 84;
        int e = e0 + le;
        float v;
        if (d == 0)      v = D0p[e];
        else if (d < 10) v = D1p[e * 9  + (d - 1)];
        else if (d < 35) v = D2p[e * 25 + (d - 10)];
        else             v = D3p[e * 49 + (d - 35)];
        Dsh[le][d] = v;
    }
    if (tid >= 64 && tid < 64 + EPB) {
        const int le = tid - 64;
        const int stride = mm_sh;
        const size_t e = (size_t)e0 + le;
        int mv;
        if (stride == 1)      mv = ((const unsigned char*)maskp)[e]      != 0;
        else if (stride == 2) mv = ((const unsigned short*)maskp)[e]     != 0;
        else if (stride == 4) mv = ((const unsigned int*)maskp)[e]       != 0u;
        else                  mv = ((const unsigned long long*)maskp)[e] != 0ULL;
        me_sh[le] = mv ? 1.0f : 0.0f;
    }
    __syncthreads();

    // ---- phase A: coalesced x staging (Y region as f32) + wave-local rotate ----
    {
        float (*XF)[1024] = reinterpret_cast<float(*)[1024]>(Y_lds);  // 8 rows f32
        #pragma unroll
        for (int s = 0; s < 2; ++s) {
            const int e  = s * 8 + w;        // this wave's edge
            const int sw = (e & 7) << 3;
            {
                const float4* src = (const float4*)(x + (size_t)(e0 + e) * 1024);
                float4* dst = (float4*)XF[w];
                #pragma unroll
                for (int t = 0; t < 4; ++t) dst[lane + t * 64] = src[lane + t * 64];
            }
            const float* xr = XF[w];
            const int ch = lane;
            A_lds[e][ch ^ sw] = f2bb(xr[ch] * Dsh[e][0]);
            #pragma unroll
            for (int l = 1; l <= 3; ++l) {
                const int n   = 2 * l + 1;
                const int off = 64 * l * l;
                const int odl = (l == 1) ? 1 : (l == 2) ? 10 : 35;
                float xv[7];
                #pragma unroll
                for (int j = 0; j < n; ++j) xv[j] = xr[off + ch * n + j];
                #pragma unroll
                for (int i = 0; i < n; ++i) {
                    float v = 0.f;
                    #pragma unroll
                    for (int j = 0; j < n; ++j) v += xv[j] * Dsh[e][odl + j * n + i];
                    int col;
                    if (i == l) col = l * 64 + ch;
                    else if (i < l) {        // neg block of m = l-i
                        const int m = l - i;
                        const int segb = (m == 1) ? 256 : (m == 2) ? 640 : 896;
                        col = segb + i * 64 + ch;
                    } else {                 // pos block of m = i-l
                        const int m = i - l;
                        const int segb = (m == 1) ? 256 : (m == 2) ? 640 : 896;
                        const int cs   = (m == 1) ? 192 : (m == 2) ? 128 : 64;
                        col = segb + cs + (2 * l - i) * 64 + ch;
                    }
                    A_lds[e][col ^ sw] = f2bb(v);
                }
            }
        }
    }
    __syncthreads();   // A complete; XF (Y region) dead

    {   // ---- phase B: 8 units per wave, m uniform per step ----
        run_unit<0>(A_lds, Y_lds, Bb, weightp, b0, me_sh, e0, w,      lane);
        run_unit<0>(A_lds, Y_lds, Bb, weightp, b0, me_sh, e0, w + 8,  lane);
        run_unit<1>(A_lds, Y_lds, Bb, weightp, b0, me_sh, e0, w,      lane);
        run_unit<1>(A_lds, Y_lds, Bb, weightp, b0, me_sh, e0, w + 8,  lane);
        run_unit<1>(A_lds, Y_lds, Bb, weightp, b0, me_sh, e0, w + 16, lane);
        run_unit<2>(A_lds, Y_lds, Bb, weightp, b0, me_sh, e0, w,      lane);
        run_unit<2>(A_lds, Y_lds, Bb, weightp, b0, me_sh, e0, w + 8,  lane);
        run_unit<3>(A_lds, Y_lds, Bb, weightp, b0, me_sh, e0, w,      lane);
    }
    __syncthreads();   // Y complete; A dead

    {   // ---- phase C: wave-local inverse rotate -> A region f32, coalesced store ----
        float (*OF)[1024] = reinterpret_cast<float(*)[1024]>(A_lds);  // 8 rows f32
        #pragma unroll
        for (int s = 0; s < 2; ++s) {
            const int e  = s * 8 + w;
            const int ch = lane;
            OF[w][ch] = bb2f(Y_lds[e][ch]) * Dsh[e][0];
            #pragma unroll
            for (int l = 1; l <= 3; ++l) {
                const int n   = 2 * l + 1;
                const int off = 64 * l * l;
                const int odl = (l == 1) ? 1 : (l == 2) ? 10 : 35;
                float yv[7];
                #pragma unroll
                for (int j = 0; j < n; ++j) yv[j] = bb2f(Y_lds[e][off + ch * n + j]);
                #pragma unroll
                for (int i = 0; i < n; ++i) {
                    float o = 0.f;
                    #pragma unroll
                    for (int j = 0; j < n; ++j) o += yv[j] * Dsh[e][odl + i * n + j];
                    OF[w][off + ch * n + i] = o;
                }
            }
            float4* dst = (float4*)(out + (size_t)(e0 + e) * 1024);
            const float4* srcv = (const float4*)OF[w];
            #pragma unroll
            for (int t = 0; t < 4; ++t) dst[lane + t * 64] = srcv[lane + t * 64];
        }
    }
}

// ---------------- scalar fallback (round-8, known-good) ----------------
__device__ int classify_buf(const void* p)
{
    const unsigned char* b = (const unsigned char*)p;
    bool bytes01 = true;
    for (int i = 0; i < 256; ++i) if (b[i] > 1) { bytes01 = false; break; }
    if (bytes01) return 0;
    const unsigned* w = (const unsigned*)p;
    bool f32b = true, bf16b = true, f16b = true;
    for (int i = 0; i < 64; ++i) {
        unsigned v = w[i];
        if (v != 0u && v != 0x3F800000u) f32b = false;
        unsigned lo = v & 0xFFFFu, hi = v >> 16;
        if (!((lo == 0u || lo == 0x3F80u) && (hi == 0u || hi == 0x3F80u))) bf16b = false;
        if (!((lo == 0u || lo == 0x3C00u) && (hi == 0u || hi == 0x3C00u))) f16b = false;
    }
    if (f32b | bf16b | f16b) return 0;
    const float* f = (const float*)p;
    float mx = 0.f;
    for (int i = 0; i < 256; ++i) { float a = fabsf(f[i]); if (a > mx) mx = a; }
    return (mx < 0.35f) ? 1 : 2;
}

__device__ int detect_stride(const unsigned char* mb)
{
    unsigned or8[8] = {0,0,0,0,0,0,0,0};
    unsigned maxb = 0, minnz = 255;
    for (int i = 0; i < 1024; ++i) {
        unsigned v = mb[i];
        or8[i & 7] |= v;
        if (v) { if (v > maxb) maxb = v; if (v < minnz) minnz = v; }
    }
    const unsigned oddnz = or8[1] | or8[3] | or8[5] | or8[7];
    const bool intbool = (maxb <= 1u) || (maxb == 255u && minnz == 255u);
    if (intbool) {
        if (oddnz)                return 1;
        else if (or8[2] | or8[6]) return 2;
        else if (or8[4])          return 4;
        else                      return 8;
    } else {
        if (or8[0])               return 2;
        else if (or8[1])          return 2;
        else if (or8[2])          return 4;
        else                      return 8;
    }
}

template<int M>
__device__ void seg_m(const __hip_bfloat16 XN[1024][9], int le,
                      const float* __restrict__ Wm, int j0, float* val)
{
    constexpr int C = 64 * (4 - M);
    const bool side = (j0 < C);
    const float* w1 = Wm + (size_t)j0 * C;
    const float* w2 = Wm + (size_t)(side ? j0 + C : j0 - C) * C;
    float acc0[16], acc1[16];
    #pragma unroll
    for (int u = 0; u < 16; ++u) { acc0[u] = 0.f; acc1[u] = 0.f; }
    #pragma unroll
    for (int lq = 0; lq <= 3 - M; ++lq) {
        const int l = M + lq, n = 2 * l + 1;
        const int a0 = 64 * l * l + l;
        for (int ch = 0; ch < 64; ch += 4) {
            const int b0_ = a0 + (ch + 0) * n, b1_ = a0 + (ch + 1) * n;
            const int b2_ = a0 + (ch + 2) * n, b3_ = a0 + (ch + 3) * n;
            const float xn0 = bf2f(XN[b0_ - M][le]), xp0 = bf2f(XN[b0_ + M][le]);
            const float xn1 = bf2f(XN[b1_ - M][le]), xp1 = bf2f(XN[b1_ + M][le]);
            const float xn2 = bf2f(XN[b2_ - M][le]), xp2 = bf2f(XN[b2_ + M][le]);
            const float xn3 = bf2f(XN[b3_ - M][le]), xp3 = bf2f(XN[b3_ + M][le]);
            const int p = lq * 64 + ch;
            #pragma unroll
            for (int u = 0; u < 16; ++u) {
                const float4 w1v = *(const float4*)(w1 + u * C + p);
                acc0[u] += xn0 * w1v.x + xn1 * w1v.y + xn2 * w1v.z + xn3 * w1v.w;
                const float4 w2v = *(const float4*)(w2 + u * C + p);
                acc1[u] += xp0 * w2v.x + xp1 * w2v.y + xp2 * w2v.z + xp3 * w2v.w;
            }
        }
    }
    #pragma unroll
    for (int u = 0; u < 16; ++u) val[u] = (side ? acc0[u] : -acc0[u]) + acc1[u];
}

__device__ void seg_m0(const __hip_bfloat16 XN[1024][9], int le,
                       const float* __restrict__ W0, const float* __restrict__ b0,
                       int j0, float* val)
{
    const float* w = W0 + (size_t)j0 * 256;
    float acc[16];
    #pragma unroll
    for (int u = 0; u < 16; ++u) acc[u] = 0.f;
    #pragma unroll
    for (int l = 0; l < 4; ++l) {
        const int n = 2 * l + 1, a0 = 64 * l * l + l;
        for (int ch = 0; ch < 64; ch += 4) {
            const float x0 = bf2f(XN[a0 + (ch + 0) * n][le]);
            const float x1 = bf2f(XN[a0 + (ch + 1) * n][le]);
            const float x2 = bf2f(XN[a0 + (ch + 2) * n][le]);
            const float x3 = bf2f(XN[a0 + (ch + 3) * n][le]);
            const int k = l * 64 + ch;
            #pragma unroll
            for (int u = 0; u < 16; ++u) {
                const float4 wv = *(const float4*)(w + u * 256 + k);
                acc[u] += x0 * wv.x + x1 * wv.y + x2 * wv.z + x3 * wv.w;
            }
        }
    }
    #pragma unroll
    for (int u = 0; u < 16; ++u) val[u] = acc[u] + b0[j0 + u];
}

__launch_bounds__(512)
__global__ void so2_scalar(const float* __restrict__ x,
                           const void* __restrict__ t0,
                           const void* __restrict__ t1,
                           const void* __restrict__ t2,
                           const float* __restrict__ D1p,
                           const float* __restrict__ D2p,
                           const float* __restrict__ D3p,
                           const float* __restrict__ weightp,
                           const float* __restrict__ b0,
                           const float* __restrict__ W1,
                           const float* __restrict__ W2,
                           const float* __restrict__ W3,
                           float* __restrict__ out)
{
    __shared__ __hip_bfloat16 XN[1024][9];
    __shared__ __hip_bfloat16 ON[1024][9];
    __shared__ float Dsh[8][84];
    __shared__ float me_sh[8];
    __shared__ int   mm_sh;
    __shared__ const void*  sel_mask;
    __shared__ const float* sel_W0;
    __shared__ const float* sel_D0;

    const int tid = threadIdx.x;
    const int e0  = blockIdx.x * 8;

    if (tid == 0) {
        int c0 = classify_buf(t0), c1 = classify_buf(t1), c2 = classify_buf(t2);
        const void* sel[3];
        if (c0 != c1 && c0 != c2 && c1 != c2) { sel[c0] = t0; sel[c1] = t1; sel[c2] = t2; }
        else { sel[2] = t0; sel[0] = t1; sel[1] = t2; }
        sel_mask = sel[0];
        sel_W0   = (const float*)sel[1];
        sel_D0   = (const float*)sel[2];
        mm_sh = detect_stride((const unsigned char*)sel[0]);
    }
    __syncthreads();

    const float* D0p   = sel_D0;
    const float* W0    = sel_W0;
    const void*  maskp = sel_mask;

    for (int idx = tid; idx < 8 * 84; idx += 512) {
        int le = idx / 84, d = idx - le * 84;
        int e = e0 + le;
        float v;
        if (d == 0)      v = D0p[e];
        else if (d < 10) v = D1p[e * 9  + (d - 1)];
        else if (d < 35) v = D2p[e * 25 + (d - 10)];
        else             v = D3p[e * 49 + (d - 35)];
        Dsh[le][d] = v;
    }
    if (tid >= 64 && tid < 72) {
        const int le = tid - 64;
        const int stride = mm_sh;
        const size_t e = (size_t)e0 + le;
        int mv;
        if (stride == 1)      mv = ((const unsigned char*)maskp)[e]      != 0;
        else if (stride == 2) mv = ((const unsigned short*)maskp)[e]     != 0;
        else if (stride == 4) mv = ((const unsigned int*)maskp)[e]       != 0u;
        else                  mv = ((const unsigned long long*)maskp)[e] != 0ULL;
        me_sh[le] = mv ? 1.0f : 0.0f;
    }
    __syncthreads();

    {
        const int le = tid >> 6;
        const int ch = tid & 63;
        const float* xr = x + (size_t)(e0 + le) * 1024;
        XN[ch][le] = __float2bfloat16(xr[ch] * Dsh[le][0]);
        #pragma unroll
        for (int l = 1; l <= 3; ++l) {
            const int n   = 2 * l + 1;
            const int off = 64 * l * l;
            const int odl = (l == 1) ? 1 : (l == 2) ? 10 : 35;
            float xv[7];
            #pragma unroll
            for (int j = 0; j < n; ++j) xv[j] = xr[off + ch * n + j];
            #pragma unroll
            for (int i = 0; i < n; ++i) {
                float v = 0.f;
                #pragma unroll
                for (int j = 0; j < n; ++j) v += xv[j] * Dsh[le][odl + j * n + i];
                XN[off + ch * n + i][le] = __float2bfloat16(v);
            }
        }
    }
    __syncthreads();

    {
        const int g  = tid >> 3;
        const int le = tid & 7;
        const float mew = me_sh[le];
        const float* wrow = weightp + (size_t)(e0 + le) * 640;
        float val[16];
        int m, j0, c, wsl;
        if (g < 16)      { m = 0; j0 = g * 16;        c = 256; wsl = 0;   }
        else if (g < 40) { m = 1; j0 = (g - 16) * 16; c = 192; wsl = 256; }
        else if (g < 56) { m = 2; j0 = (g - 40) * 16; c = 128; wsl = 448; }
        else             { m = 3; j0 = (g - 56) * 16; c = 64;  wsl = 576; }

        if      (m == 0) seg_m0(XN, le, W0, b0, j0, val);
        else if (m == 1) seg_m<1>(XN, le, W1, j0, val);
        else if (m == 2) seg_m<2>(XN, le, W2, j0, val);
        else             seg_m<3>(XN, le, W3, j0, val);

        #pragma unroll
        for (int u = 0; u < 16; ++u) {
            const int j  = j0 + u;
            const int wo = (j < c) ? j : j - c;
            const float v = val[u] * wrow[wsl + wo] * mew;
            int tgt;
            if (m == 0) { const int l = j >> 6, ch = j & 63; tgt = 64 * l * l + l + ch * (2 * l + 1); }
            else {
                const int p = j >> 1, s = j & 1;
                const int l = m + (p >> 6), ch = p & 63;
                tgt = 64 * l * l + l + ch * (2 * l + 1) + (s ? m : -m);
            }
            ON[tgt][le] = __float2bfloat16(v);
        }
    }
    __syncthreads();

    {
        const int le = tid >> 6;
        const int ch = tid & 63;
        float* orow = out + (size_t)(e0 + le) * 1024;
        orow[ch] = bf2f(ON[ch][le]) * Dsh[le][0];
        #pragma unroll
        for (int l = 1; l <= 3; ++l) {
            const int n   = 2 * l + 1;
            const int off = 64 * l * l;
            const int odl = (l == 1) ? 1 : (l == 2) ? 10 : 35;
            float yv[7];
            #pragma unroll
            for (int j = 0; j < n; ++j) yv[j] = bf2f(ON[off + ch * n + j][le]);
            #pragma unroll
            for (int i = 0; i < n; ++i) {
                float o = 0.f;
                #pragma unroll
                for (int j = 0; j < n; ++j) o += yv[j] * Dsh[le][odl + i * n + j];
                orow[off + ch * n + i] = o;
            }
        }
    }
}

extern "C" void kernel_launch(void* const* d_in, const int* in_sizes, int n_in,
                              void* d_out, int out_size, void* d_ws, size_t ws_size,
                              hipStream_t stream)
{
    const float *x = nullptr, *D1p = nullptr, *D2p = nullptr, *D3p = nullptr;
    const float *weight = nullptr, *b0 = nullptr, *W1 = nullptr, *W2 = nullptr, *W3 = nullptr;
    const void* trio[3] = {nullptr, nullptr, nullptr};
    int nt = 0;
    bool ok = (n_in == 12);
    if (ok) {
        for (int i = 0; i < 12; ++i) {
            switch (in_sizes[i]) {
                case 67108864: x      = (const float*)d_in[i]; break;
                case 589824:   D1p    = (const float*)d_in[i]; break;
                case 1638400:  D2p    = (const float*)d_in[i]; break;
                case 3211264:  D3p    = (const float*)d_in[i]; break;
                case 41943040: weight = (const float*)d_in[i]; break;
                case 256:      b0     = (const float*)d_in[i]; break;
                case 73728:    W1     = (const float*)d_in[i]; break;
                case 32768:    W2     = (const float*)d_in[i]; break;
                case 8192:     W3     = (const float*)d_in[i]; break;
                case 65536:    if (nt < 3) trio[nt++] = d_in[i]; break;
                default: break;
            }
        }
        ok = x && D1p && D2p && D3p && weight && b0 && W1 && W2 && W3 && (nt == 3);
    }
    if (!ok) {
        x      = (const float*)d_in[0];
        trio[0] = d_in[1];
        D1p    = (const float*)d_in[2];
        D2p    = (const float*)d_in[3];
        D3p    = (const float*)d_in[4];
        weight = (const float*)d_in[5];
        trio[1] = d_in[6];
        trio[2] = d_in[7];
        b0     = (const float*)d_in[8];
        W1     = (const float*)d_in[9];
        W2     = (const float*)d_in[10];
        W3     = (const float*)d_in[11];
    }
    float* out = (float*)d_out;
    const int E = out_size / 1024;

    if (ws_size >= (size_t)WS_NEED) {
        ushort* Bb = (ushort*)d_ws;
        so2_prep<<<576, 64, 0, stream>>>(trio[0], trio[1], trio[2], W1, W2, W3, Bb);
        so2_mfma<<<E / EPB, 512, 0, stream>>>(x, trio[0], trio[1], trio[2],
                                              D1p, D2p, D3p, weight, b0, Bb, out);
    } else {
        so2_scalar<<<E / 8, 512, 0, stream>>>(x, trio[0], trio[1], trio[2],
                                              D1p, D2p, D3p, weight,
                                              b0, W1, W2, W3, out);
    }

    hipError_t lerr = hipGetLastError();
    if (lerr != hipSuccess) {
        unsigned char pat = (unsigned char)(0x60 | ((unsigned)lerr & 0xF));
        hipMemsetAsync(d_out, pat, (size_t)out_size * 4, stream);
    }
}

// Round 20
// 284.431 us; speedup vs baseline: 1.1190x; 1.1190x over previous
//
#include <hip/hip_runtime.h>
#include <hip/hip_bf16.h>

// SO2Linear, round 20: r16 with chunk-2 brick prefetch (final frontier cell).
//   Measured frontier: >64 VGPR -> 1 block/CU (335us); 64 VGPR + chunk-4
//   -> 2 blocks but 104MB spill (313us). Natural demand is ~72 regs; the
//   chunk-4 brick buffer holds 16. Chunk-2 (8 regs) removes exactly the
//   8-reg overage -> target: 2 blocks AND no spill within the 64-reg cap.
// Everything else byte-identical to r16/r18 (best: 292.5us wall).

#define EPB 16
#define BRICK_USHORTS 294912
#define WS_NEED (589824 + 16)

typedef __attribute__((ext_vector_type(8))) short short8v;
typedef __attribute__((ext_vector_type(4))) float float4v;
typedef unsigned short ushort;

__device__ __forceinline__ float bf2f(__hip_bfloat16 v) { return __bfloat162float(v); }
__device__ __forceinline__ ushort f2bb(float v) {
    __hip_bfloat16 h = __float2bfloat16(v);
    return *reinterpret_cast<ushort*>(&h);
}
__device__ __forceinline__ float bb2f(ushort u) {
    __hip_bfloat16 h = *reinterpret_cast<__hip_bfloat16*>(&u);
    return __bfloat162float(h);
}

// ---- wave-parallel trio classification ----
// 0 = mask (boolean), 1 = W0 (0.05-scale), 2 = D0 (unit-scale)
__device__ int classify_wave(const void* p, int lane)
{
    const unsigned char* b = (const unsigned char*)p;
    bool ok01 = true;
    #pragma unroll
    for (int j = 0; j < 4; ++j) if (b[lane * 4 + j] > 1) ok01 = false;
    if (__all(ok01)) return 0;
    const unsigned* w = (const unsigned*)p;
    const unsigned v = w[lane];
    const unsigned lo = v & 0xFFFFu, hi = v >> 16;
    const bool f32b  = (v == 0u || v == 0x3F800000u);
    const bool bf16b = (lo == 0u || lo == 0x3F80u) && (hi == 0u || hi == 0x3F80u);
    const bool f16b  = (lo == 0u || lo == 0x3C00u) && (hi == 0u || hi == 0x3C00u);
    if (__all(f32b) | __all(bf16b) | __all(f16b)) return 0;
    const float* f = (const float*)p;
    float mx = 0.f;
    #pragma unroll
    for (int j = 0; j < 4; ++j) mx = fmaxf(mx, fabsf(f[lane * 4 + j]));
    #pragma unroll
    for (int d = 1; d < 64; d <<= 1) mx = fmaxf(mx, __shfl_xor(mx, d));
    return (mx < 0.35f) ? 1 : 2;
}

__device__ int detect_stride_wave(const unsigned char* mb, int lane)
{
    unsigned orr[8] = {0,0,0,0,0,0,0,0};
    unsigned maxb = 0, minnz = 255;
    #pragma unroll
    for (int j = 0; j < 16; ++j) {
        unsigned v = mb[lane * 16 + j];
        orr[j & 7] |= v;
        if (v) { maxb = max(maxb, v); minnz = min(minnz, v); }
    }
    #pragma unroll
    for (int d = 1; d < 64; d <<= 1) {
        #pragma unroll
        for (int r = 0; r < 8; ++r) orr[r] |= (unsigned)__shfl_xor((int)orr[r], d);
        maxb  = max(maxb, (unsigned)__shfl_xor((int)maxb, d));
        minnz = min(minnz, (unsigned)__shfl_xor((int)minnz, d));
    }
    const unsigned oddnz = orr[1] | orr[3] | orr[5] | orr[7];
    const bool intbool = (maxb <= 1u) || (maxb == 255u && minnz == 255u);
    if (intbool) {
        if (oddnz)                  return 1;
        else if (orr[2] | orr[6])   return 2;
        else if (orr[4])            return 4;
        else                        return 8;
    } else {
        if (orr[0])                 return 2;
        else if (orr[1])            return 2;
        else if (orr[2])            return 4;
        else                        return 8;
    }
}

// ---------------- prep: pack Bhat bricks + write routing header ----------------
__global__ void so2_prep(const void* t0, const void* t1, const void* t2,
                         const float* __restrict__ W1,
                         const float* __restrict__ W2,
                         const float* __restrict__ W3,
                         ushort* __restrict__ Bb)
{
    const int lane = threadIdx.x;            // blockDim = 64, one wave
    const int c0 = classify_wave(t0, lane);
    const int c1 = classify_wave(t1, lane);
    const int c2 = classify_wave(t2, lane);
    const void* sel[3];
    int im, id;
    if (c0 != c1 && c0 != c2 && c1 != c2) {
        sel[c0] = t0; sel[c1] = t1; sel[c2] = t2;
        im = (c0 == 0) ? 0 : (c1 == 0) ? 1 : 2;
        id = (c0 == 2) ? 0 : (c1 == 2) ? 1 : 2;
    } else {
        sel[2] = t0; sel[0] = t1; sel[1] = t2;   // dict-order fallback
        im = 1; id = 0;
    }
    const float* sW0 = (const float*)sel[1];
    if (blockIdx.x == 0) {
        const int stride = detect_stride_wave((const unsigned char*)sel[0], lane);
        if (lane == 0) {
            int* hdr = (int*)(Bb + BRICK_USHORTS);
            hdr[0] = im; hdr[1] = id; hdr[2] = stride;
        }
    }

    const int brick = blockIdx.x;            // 576 bricks
    int m, r, KT;
    if (brick < 128)      { m = 0; r = brick;       KT = 8;  }
    else if (brick < 416) { m = 1; r = brick - 128; KT = 12; }
    else if (brick < 544) { m = 2; r = brick - 416; KT = 8;  }
    else                  { m = 3; r = brick - 544; KT = 4;  }
    const int nt = r / KT, kt = r - nt * KT;
    const float* Wm = (m == 0) ? sW0 : (m == 1) ? W1 : (m == 2) ? W2 : W3;
    const int c = (m == 0) ? 256 : (m == 1) ? 192 : (m == 2) ? 128 : 64;

    const int col = nt * 16 + (lane & 15);
    const int kb  = kt * 32 + (lane >> 4) * 8;
    ushort* dst = Bb + ((size_t)brick << 9) + lane * 8;
    #pragma unroll
    for (int i = 0; i < 8; ++i) {
        const int k = kb + i;
        float v;
        if (m == 0) v = Wm[(size_t)col * 256 + k];
        else if (col < c) v = (k < c) ? Wm[(size_t)col * c + k]
                                      : Wm[(size_t)(c + col) * c + (k - c)];
        else {
            const int o = col - c;
            v = (k < c) ? -Wm[(size_t)(c + o) * c + k]
                        :  Wm[(size_t)o * c + (k - c)];
        }
        dst[i] = f2bb(v);
    }
}

// ---------------- phase-B unit (compile-time M/KT, chunk-2 brick prefetch) -----
template<int M>
__device__ __forceinline__ void run_unit(
    const ushort (*A_lds)[1024], ushort (*Y_lds)[1024],
    const ushort* __restrict__ Bb,
    const float* __restrict__ weightp, const float* __restrict__ b0,
    const float* me_sh, int e0, int nt, int lane)
{
    constexpr int KT   = (M == 0) ? 8 : (M == 1) ? 12 : (M == 2) ? 8 : 4;
    constexpr int segk = (M == 0) ? 0 : (M == 1) ? 256 : (M == 2) ? 640 : 896;
    constexpr int c    = (M == 0) ? 256 : (M == 1) ? 192 : (M == 2) ? 128 : 64;
    constexpr int wsl  = (M == 0) ? 0 : (M == 1) ? 256 : (M == 2) ? 448 : 576;
    constexpr int bb   = (M == 0) ? 0 : (M == 1) ? 128 : (M == 2) ? 416 : 544;

    const int row16 = lane & 15;
    const int kg    = lane >> 4;
    const int sw    = (row16 & 7) << 3;

    const ushort* bp = Bb + (((size_t)(bb + nt * KT)) << 9) + lane * 8;
    const int k0 = segk + kg * 8;
    float4v acc = {0.f, 0.f, 0.f, 0.f};

    #pragma unroll
    for (int kc = 0; kc < KT; kc += 2) {     // chunked prefetch: 8 VGPRs peak
        short8v bv[2];
        #pragma unroll
        for (int q = 0; q < 2; ++q)
            bv[q] = *(const short8v*)(bp + (size_t)(kc + q) * 512);
        #pragma unroll
        for (int q = 0; q < 2; ++q) {
            short8v av = *(const short8v*)&A_lds[row16][(k0 + (kc + q) * 32) ^ sw];
            acc = __builtin_amdgcn_mfma_f32_16x16x32_bf16(av, bv[q], acc, 0, 0, 0);
        }
    }

    const int j  = nt * 16 + row16;
    const int wo = (j < c) ? j : j - c;
    int tgt;
    if (M == 0) { const int l = j >> 6, ch = j & 63; tgt = 64*l*l + l + ch*(2*l+1); }
    else {
        const int p = j >> 1, s = j & 1;
        const int l = M + (p >> 6), ch = p & 63;
        tgt = 64*l*l + l + ch*(2*l+1) + (s ? M : -M);
    }
    const float bias = (M == 0) ? b0[j] : 0.f;
    #pragma unroll
    for (int r = 0; r < 4; ++r) {
        const int e = kg * 4 + r;
        const float v = (acc[r] + bias)
                      * weightp[(size_t)(e0 + e) * 640 + wsl + wo]
                      * me_sh[e];
        Y_lds[e][tgt] = f2bb(v);
    }
}

// ---------------- main MFMA kernel ----------------
__launch_bounds__(512, 4)
__global__ void so2_mfma(const float* __restrict__ x,
                         const void* __restrict__ t0,
                         const void* __restrict__ t1,
                         const void* __restrict__ t2,
                         const float* __restrict__ D1p,
                         const float* __restrict__ D2p,
                         const float* __restrict__ D3p,
                         const float* __restrict__ weightp,
                         const float* __restrict__ b0,
                         const ushort* __restrict__ Bb,
                         float* __restrict__ out)
{
    __shared__ ushort A_lds[EPB][1024];      // 32 KB
    __shared__ ushort Y_lds[EPB][1024];      // 32 KB
    __shared__ float Dsh[EPB][84];
    __shared__ float me_sh[EPB];
    __shared__ int   mm_sh;
    __shared__ const void*  sel_mask;
    __shared__ const float* sel_D0;

    const int tid  = threadIdx.x;
    const int e0   = blockIdx.x * EPB;
    const int w    = tid >> 6;               // wave 0..7
    const int lane = tid & 63;

    if (tid == 0) {
        const int* hdr = (const int*)(Bb + BRICK_USHORTS);
        const void* tarr[3] = {t0, t1, t2};
        sel_mask = tarr[hdr[0]];
        sel_D0   = (const float*)tarr[hdr[1]];
        mm_sh    = hdr[2];
    }
    __syncthreads();

    const float* D0p   = sel_D0;
    const void*  maskp = sel_mask;

    for (int idx = tid; idx < EPB * 84; idx += 512) {
        int le = idx / 84, d = idx - le * 84;
        int e = e0 + le;
        float v;
        if (d == 0)      v = D0p[e];
        else if (d < 10) v = D1p[e * 9  + (d - 1)];
        else if (d < 35) v = D2p[e * 25 + (d - 10)];
        else             v = D3p[e * 49 + (d - 35)];
        Dsh[le][d] = v;
    }
    if (tid >= 64 && tid < 64 + EPB) {
        const int le = tid - 64;
        const int stride = mm_sh;
        const size_t e = (size_t)e0 + le;
        int mv;
        if (stride == 1)      mv = ((const unsigned char*)maskp)[e]      != 0;
        else if (stride == 2) mv = ((const unsigned short*)maskp)[e]     != 0;
        else if (stride == 4) mv = ((const unsigned int*)maskp)[e]       != 0u;
        else                  mv = ((const unsigned long long*)maskp)[e] != 0ULL;
        me_sh[le] = mv ? 1.0f : 0.0f;
    }
    __syncthreads();

    // ---- phase A: coalesced x staging (Y region as f32) + wave-local rotate ----
    {
        float (*XF)[1024] = reinterpret_cast<float(*)[1024]>(Y_lds);  // 8 rows f32
        #pragma unroll
        for (int s = 0; s < 2; ++s) {
            const int e  = s * 8 + w;        // this wave's edge
            const int sw = (e & 7) << 3;
            {
                const float4* src = (const float4*)(x + (size_t)(e0 + e) * 1024);
                float4* dst = (float4*)XF[w];
                #pragma unroll
                for (int t = 0; t < 4; ++t) dst[lane + t * 64] = src[lane + t * 64];
            }
            const float* xr = XF[w];
            const int ch = lane;
            A_lds[e][ch ^ sw] = f2bb(xr[ch] * Dsh[e][0]);
            #pragma unroll
            for (int l = 1; l <= 3; ++l) {
                const int n   = 2 * l + 1;
                const int off = 64 * l * l;
                const int odl = (l == 1) ? 1 : (l == 2) ? 10 : 35;
                float xv[7];
                #pragma unroll
                for (int j = 0; j < n; ++j) xv[j] = xr[off + ch * n + j];
                #pragma unroll
                for (int i = 0; i < n; ++i) {
                    float v = 0.f;
                    #pragma unroll
                    for (int j = 0; j < n; ++j) v += xv[j] * Dsh[e][odl + j * n + i];
                    int col;
                    if (i == l) col = l * 64 + ch;
                    else if (i < l) {        // neg block of m = l-i
                        const int m = l - i;
                        const int segb = (m == 1) ? 256 : (m == 2) ? 640 : 896;
                        col = segb + i * 64 + ch;
                    } else {                 // pos block of m = i-l
                        const int m = i - l;
                        const int segb = (m == 1) ? 256 : (m == 2) ? 640 : 896;
                        const int cs   = (m == 1) ? 192 : (m == 2) ? 128 : 64;
                        col = segb + cs + (2 * l - i) * 64 + ch;
                    }
                    A_lds[e][col ^ sw] = f2bb(v);
                }
            }
        }
    }
    __syncthreads();   // A complete; XF (Y region) dead

    {   // ---- phase B: 8 units per wave, m uniform per step ----
        run_unit<0>(A_lds, Y_lds, Bb, weightp, b0, me_sh, e0, w,      lane);
        run_unit<0>(A_lds, Y_lds, Bb, weightp, b0, me_sh, e0, w + 8,  lane);
        run_unit<1>(A_lds, Y_lds, Bb, weightp, b0, me_sh, e0, w,      lane);
        run_unit<1>(A_lds, Y_lds, Bb, weightp, b0, me_sh, e0, w + 8,  lane);
        run_unit<1>(A_lds, Y_lds, Bb, weightp, b0, me_sh, e0, w + 16, lane);
        run_unit<2>(A_lds, Y_lds, Bb, weightp, b0, me_sh, e0, w,      lane);
        run_unit<2>(A_lds, Y_lds, Bb, weightp, b0, me_sh, e0, w + 8,  lane);
        run_unit<3>(A_lds, Y_lds, Bb, weightp, b0, me_sh, e0, w,      lane);
    }
    __syncthreads();   // Y complete; A dead

    {   // ---- phase C: wave-local inverse rotate -> A region f32, coalesced store ----
        float (*OF)[1024] = reinterpret_cast<float(*)[1024]>(A_lds);  // 8 rows f32
        #pragma unroll
        for (int s = 0; s < 2; ++s) {
            const int e  = s * 8 + w;
            const int ch = lane;
            OF[w][ch] = bb2f(Y_lds[e][ch]) * Dsh[e][0];
            #pragma unroll
            for (int l = 1; l <= 3; ++l) {
                const int n   = 2 * l + 1;
                const int off = 64 * l * l;
                const int odl = (l == 1) ? 1 : (l == 2) ? 10 : 35;
                float yv[7];
                #pragma unroll
                for (int j = 0; j < n; ++j) yv[j] = bb2f(Y_lds[e][off + ch * n + j]);
                #pragma unroll
                for (int i = 0; i < n; ++i) {
                    float o = 0.f;
                    #pragma unroll
                    for (int j = 0; j < n; ++j) o += yv[j] * Dsh[e][odl + i * n + j];
                    OF[w][off + ch * n + i] = o;
                }
            }
            float4* dst = (float4*)(out + (size_t)(e0 + e) * 1024);
            const float4* srcv = (const float4*)OF[w];
            #pragma unroll
            for (int t = 0; t < 4; ++t) dst[lane + t * 64] = srcv[lane + t * 64];
        }
    }
}

// ---------------- scalar fallback (round-8, known-good) ----------------
__device__ int classify_buf(const void* p)
{
    const unsigned char* b = (const unsigned char*)p;
    bool bytes01 = true;
    for (int i = 0; i < 256; ++i) if (b[i] > 1) { bytes01 = false; break; }
    if (bytes01) return 0;
    const unsigned* w = (const unsigned*)p;
    bool f32b = true, bf16b = true, f16b = true;
    for (int i = 0; i < 64; ++i) {
        unsigned v = w[i];
        if (v != 0u && v != 0x3F800000u) f32b = false;
        unsigned lo = v & 0xFFFFu, hi = v >> 16;
        if (!((lo == 0u || lo == 0x3F80u) && (hi == 0u || hi == 0x3F80u))) bf16b = false;
        if (!((lo == 0u || lo == 0x3C00u) && (hi == 0u || hi == 0x3C00u))) f16b = false;
    }
    if (f32b | bf16b | f16b) return 0;
    const float* f = (const float*)p;
    float mx = 0.f;
    for (int i = 0; i < 256; ++i) { float a = fabsf(f[i]); if (a > mx) mx = a; }
    return (mx < 0.35f) ? 1 : 2;
}

__device__ int detect_stride(const unsigned char* mb)
{
    unsigned or8[8] = {0,0,0,0,0,0,0,0};
    unsigned maxb = 0, minnz = 255;
    for (int i = 0; i < 1024; ++i) {
        unsigned v = mb[i];
        or8[i & 7] |= v;
        if (v) { if (v > maxb) maxb = v; if (v < minnz) minnz = v; }
    }
    const unsigned oddnz = or8[1] | or8[3] | or8[5] | or8[7];
    const bool intbool = (maxb <= 1u) || (maxb == 255u && minnz == 255u);
    if (intbool) {
        if (oddnz)                return 1;
        else if (or8[2] | or8[6]) return 2;
        else if (or8[4])          return 4;
        else                      return 8;
    } else {
        if (or8[0])               return 2;
        else if (or8[1])          return 2;
        else if (or8[2])          return 4;
        else                      return 8;
    }
}

template<int M>
__device__ void seg_m(const __hip_bfloat16 XN[1024][9], int le,
                      const float* __restrict__ Wm, int j0, float* val)
{
    constexpr int C = 64 * (4 - M);
    const bool side = (j0 < C);
    const float* w1 = Wm + (size_t)j0 * C;
    const float* w2 = Wm + (size_t)(side ? j0 + C : j0 - C) * C;
    float acc0[16], acc1[16];
    #pragma unroll
    for (int u = 0; u < 16; ++u) { acc0[u] = 0.f; acc1[u] = 0.f; }
    #pragma unroll
    for (int lq = 0; lq <= 3 - M; ++lq) {
        const int l = M + lq, n = 2 * l + 1;
        const int a0 = 64 * l * l + l;
        for (int ch = 0; ch < 64; ch += 4) {
            const int b0_ = a0 + (ch + 0) * n, b1_ = a0 + (ch + 1) * n;
            const int b2_ = a0 + (ch + 2) * n, b3_ = a0 + (ch + 3) * n;
            const float xn0 = bf2f(XN[b0_ - M][le]), xp0 = bf2f(XN[b0_ + M][le]);
            const float xn1 = bf2f(XN[b1_ - M][le]), xp1 = bf2f(XN[b1_ + M][le]);
            const float xn2 = bf2f(XN[b2_ - M][le]), xp2 = bf2f(XN[b2_ + M][le]);
            const float xn3 = bf2f(XN[b3_ - M][le]), xp3 = bf2f(XN[b3_ + M][le]);
            const int p = lq * 64 + ch;
            #pragma unroll
            for (int u = 0; u < 16; ++u) {
                const float4 w1v = *(const float4*)(w1 + u * C + p);
                acc0[u] += xn0 * w1v.x + xn1 * w1v.y + xn2 * w1v.z + xn3 * w1v.w;
                const float4 w2v = *(const float4*)(w2 + u * C + p);
                acc1[u] += xp0 * w2v.x + xp1 * w2v.y + xp2 * w2v.z + xp3 * w2v.w;
            }
        }
    }
    #pragma unroll
    for (int u = 0; u < 16; ++u) val[u] = (side ? acc0[u] : -acc0[u]) + acc1[u];
}

__device__ void seg_m0(const __hip_bfloat16 XN[1024][9], int le,
                       const float* __restrict__ W0, const float* __restrict__ b0,
                       int j0, float* val)
{
    const float* w = W0 + (size_t)j0 * 256;
    float acc[16];
    #pragma unroll
    for (int u = 0; u < 16; ++u) acc[u] = 0.f;
    #pragma unroll
    for (int l = 0; l < 4; ++l) {
        const int n = 2 * l + 1, a0 = 64 * l * l + l;
        for (int ch = 0; ch < 64; ch += 4) {
            const float x0 = bf2f(XN[a0 + (ch + 0) * n][le]);
            const float x1 = bf2f(XN[a0 + (ch + 1) * n][le]);
            const float x2 = bf2f(XN[a0 + (ch + 2) * n][le]);
            const float x3 = bf2f(XN[a0 + (ch + 3) * n][le]);
            const int k = l * 64 + ch;
            #pragma unroll
            for (int u = 0; u < 16; ++u) {
                const float4 wv = *(const float4*)(w + u * 256 + k);
                acc[u] += x0 * wv.x + x1 * wv.y + x2 * wv.z + x3 * wv.w;
            }
        }
    }
    #pragma unroll
    for (int u = 0; u < 16; ++u) val[u] = acc[u] + b0[j0 + u];
}

__launch_bounds__(512)
__global__ void so2_scalar(const float* __restrict__ x,
                           const void* __restrict__ t0,
                           const void* __restrict__ t1,
                           const void* __restrict__ t2,
                           const float* __restrict__ D1p,
                           const float* __restrict__ D2p,
                           const float* __restrict__ D3p,
                           const float* __restrict__ weightp,
                           const float* __restrict__ b0,
                           const float* __restrict__ W1,
                           const float* __restrict__ W2,
                           const float* __restrict__ W3,
                           float* __restrict__ out)
{
    __shared__ __hip_bfloat16 XN[1024][9];
    __shared__ __hip_bfloat16 ON[1024][9];
    __shared__ float Dsh[8][84];
    __shared__ float me_sh[8];
    __shared__ int   mm_sh;
    __shared__ const void*  sel_mask;
    __shared__ const float* sel_W0;
    __shared__ const float* sel_D0;

    const int tid = threadIdx.x;
    const int e0  = blockIdx.x * 8;

    if (tid == 0) {
        int c0 = classify_buf(t0), c1 = classify_buf(t1), c2 = classify_buf(t2);
        const void* sel[3];
        if (c0 != c1 && c0 != c2 && c1 != c2) { sel[c0] = t0; sel[c1] = t1; sel[c2] = t2; }
        else { sel[2] = t0; sel[0] = t1; sel[1] = t2; }
        sel_mask = sel[0];
        sel_W0   = (const float*)sel[1];
        sel_D0   = (const float*)sel[2];
        mm_sh = detect_stride((const unsigned char*)sel[0]);
    }
    __syncthreads();

    const float* D0p   = sel_D0;
    const float* W0    = sel_W0;
    const void*  maskp = sel_mask;

    for (int idx = tid; idx < 8 * 84; idx += 512) {
        int le = idx / 84, d = idx - le * 84;
        int e = e0 + le;
        float v;
        if (d == 0)      v = D0p[e];
        else if (d < 10) v = D1p[e * 9  + (d - 1)];
        else if (d < 35) v = D2p[e * 25 + (d - 10)];
        else             v = D3p[e * 49 + (d - 35)];
        Dsh[le][d] = v;
    }
    if (tid >= 64 && tid < 72) {
        const int le = tid - 64;
        const int stride = mm_sh;
        const size_t e = (size_t)e0 + le;
        int mv;
        if (stride == 1)      mv = ((const unsigned char*)maskp)[e]      != 0;
        else if (stride == 2) mv = ((const unsigned short*)maskp)[e]     != 0;
        else if (stride == 4) mv = ((const unsigned int*)maskp)[e]       != 0u;
        else                  mv = ((const unsigned long long*)maskp)[e] != 0ULL;
        me_sh[le] = mv ? 1.0f : 0.0f;
    }
    __syncthreads();

    {
        const int le = tid >> 6;
        const int ch = tid & 63;
        const float* xr = x + (size_t)(e0 + le) * 1024;
        XN[ch][le] = __float2bfloat16(xr[ch] * Dsh[le][0]);
        #pragma unroll
        for (int l = 1; l <= 3; ++l) {
            const int n   = 2 * l + 1;
            const int off = 64 * l * l;
            const int odl = (l == 1) ? 1 : (l == 2) ? 10 : 35;
            float xv[7];
            #pragma unroll
            for (int j = 0; j < n; ++j) xv[j] = xr[off + ch * n + j];
            #pragma unroll
            for (int i = 0; i < n; ++i) {
                float v = 0.f;
                #pragma unroll
                for (int j = 0; j < n; ++j) v += xv[j] * Dsh[le][odl + j * n + i];
                XN[off + ch * n + i][le] = __float2bfloat16(v);
            }
        }
    }
    __syncthreads();

    {
        const int g  = tid >> 3;
        const int le = tid & 7;
        const float mew = me_sh[le];
        const float* wrow = weightp + (size_t)(e0 + le) * 640;
        float val[16];
        int m, j0, c, wsl;
        if (g < 16)      { m = 0; j0 = g * 16;        c = 256; wsl = 0;   }
        else if (g < 40) { m = 1; j0 = (g - 16) * 16; c = 192; wsl = 256; }
        else if (g < 56) { m = 2; j0 = (g - 40) * 16; c = 128; wsl = 448; }
        else             { m = 3; j0 = (g - 56) * 16; c = 64;  wsl = 576; }

        if      (m == 0) seg_m0(XN, le, W0, b0, j0, val);
        else if (m == 1) seg_m<1>(XN, le, W1, j0, val);
        else if (m == 2) seg_m<2>(XN, le, W2, j0, val);
        else             seg_m<3>(XN, le, W3, j0, val);

        #pragma unroll
        for (int u = 0; u < 16; ++u) {
            const int j  = j0 + u;
            const int wo = (j < c) ? j : j - c;
            const float v = val[u] * wrow[wsl + wo] * mew;
            int tgt;
            if (m == 0) { const int l = j >> 6, ch = j & 63; tgt = 64 * l * l + l + ch * (2 * l + 1); }
            else {
                const int p = j >> 1, s = j & 1;
                const int l = m + (p >> 6), ch = p & 63;
                tgt = 64 * l * l + l + ch * (2 * l + 1) + (s ? m : -m);
            }
            ON[tgt][le] = __float2bfloat16(v);
        }
    }
    __syncthreads();

    {
        const int le = tid >> 6;
        const int ch = tid & 63;
        float* orow = out + (size_t)(e0 + le) * 1024;
        orow[ch] = bf2f(ON[ch][le]) * Dsh[le][0];
        #pragma unroll
        for (int l = 1; l <= 3; ++l) {
            const int n   = 2 * l + 1;
            const int off = 64 * l * l;
            const int odl = (l == 1) ? 1 : (l == 2) ? 10 : 35;
            float yv[7];
            #pragma unroll
            for (int j = 0; j < n; ++j) yv[j] = bf2f(ON[off + ch * n + j][le]);
            #pragma unroll
            for (int i = 0; i < n; ++i) {
                float o = 0.f;
                #pragma unroll
                for (int j = 0; j < n; ++j) o += yv[j] * Dsh[le][odl + i * n + j];
                orow[off + ch * n + i] = o;
            }
        }
    }
}

extern "C" void kernel_launch(void* const* d_in, const int* in_sizes, int n_in,
                              void* d_out, int out_size, void* d_ws, size_t ws_size,
                              hipStream_t stream)
{
    const float *x = nullptr, *D1p = nullptr, *D2p = nullptr, *D3p = nullptr;
    const float *weight = nullptr, *b0 = nullptr, *W1 = nullptr, *W2 = nullptr, *W3 = nullptr;
    const void* trio[3] = {nullptr, nullptr, nullptr};
    int nt = 0;
    bool ok = (n_in == 12);
    if (ok) {
        for (int i = 0; i < 12; ++i) {
            switch (in_sizes[i]) {
                case 67108864: x      = (const float*)d_in[i]; break;
                case 589824:   D1p    = (const float*)d_in[i]; break;
                case 1638400:  D2p    = (const float*)d_in[i]; break;
                case 3211264:  D3p    = (const float*)d_in[i]; break;
                case 41943040: weight = (const float*)d_in[i]; break;
                case 256:      b0     = (const float*)d_in[i]; break;
                case 73728:    W1     = (const float*)d_in[i]; break;
                case 32768:    W2     = (const float*)d_in[i]; break;
                case 8192:     W3     = (const float*)d_in[i]; break;
                case 65536:    if (nt < 3) trio[nt++] = d_in[i]; break;
                default: break;
            }
        }
        ok = x && D1p && D2p && D3p && weight && b0 && W1 && W2 && W3 && (nt == 3);
    }
    if (!ok) {
        x      = (const float*)d_in[0];
        trio[0] = d_in[1];
        D1p    = (const float*)d_in[2];
        D2p    = (const float*)d_in[3];
        D3p    = (const float*)d_in[4];
        weight = (const float*)d_in[5];
        trio[1] = d_in[6];
        trio[2] = d_in[7];
        b0     = (const float*)d_in[8];
        W1     = (const float*)d_in[9];
        W2     = (const float*)d_in[10];
        W3     = (const float*)d_in[11];
    }
    float* out = (float*)d_out;
    const int E = out_size / 1024;

    if (ws_size >= (size_t)WS_NEED) {
        ushort* Bb = (ushort*)d_ws;
        so2_prep<<<576, 64, 0, stream>>>(trio[0], trio[1], trio[2], W1, W2, W3, Bb);
        so2_mfma<<<E / EPB, 512, 0, stream>>>(x, trio[0], trio[1], trio[2],
                                              D1p, D2p, D3p, weight, b0, Bb, out);
    } else {
        so2_scalar<<<E / 8, 512, 0, stream>>>(x, trio[0], trio[1], trio[2],
                                              D1p, D2p, D3p, weight,
                                              b0, W1, W2, W3, out);
    }

    hipError_t lerr = hipGetLastError();
    if (lerr != hipSuccess) {
        unsigned char pat = (unsigned char)(0x60 | ((unsigned)lerr & 0xF));
        hipMemsetAsync(d_out, pat, (size_t)out_size * 4, stream);
    }
}